// Round 9
// baseline (975.009 us; speedup 1.0000x reference)
//
#include <hip/hip_runtime.h>

#define T_TOK 4096
#define DM 2048
#define DF 8192
#define NE 4
#define BM 256
#define BN 64        // fallback geometry
#define GBN 128      // new-path N tile
#define GBK 64       // gemm1 K step
#define G2BK 32      // gemm2 K step (48 KB LDS -> 2 blocks/CU)
#define BKO 32
#define MAX_TILES 20
#define PADROWS 256
#define LDK (BKO + 8)

typedef __attribute__((ext_vector_type(8))) short short8;
typedef __attribute__((ext_vector_type(4))) float f32x4;

__device__ __forceinline__ unsigned short f2bf(float f) {
  unsigned int u = __float_as_uint(f);
  u += 0x7fffu + ((u >> 16) & 1u);   // round-to-nearest-even
  return (unsigned short)(u >> 16);
}

// async global->LDS, 16B/lane; LDS base wave-uniform (HW: base + lane*16)
__device__ __forceinline__ void gld_lds16(const unsigned short* g, unsigned short* l) {
  __builtin_amdgcn_global_load_lds(
      (const __attribute__((address_space(1))) unsigned int*)g,
      (__attribute__((address_space(3))) unsigned int*)l, 16, 0, 0);
}

// ---------------- router ----------------
__global__ __launch_bounds__(256) void router_kernel(
    const float* __restrict__ x, const float* __restrict__ Wr,
    const float* __restrict__ br, int* __restrict__ top_idx,
    float* __restrict__ top_w, int* __restrict__ counts) {
  int tok = (blockIdx.x * blockDim.x + threadIdx.x) >> 6;
  int lane = threadIdx.x & 63;
  if (tok >= T_TOK) return;
  const float* xr = x + (size_t)tok * DM;
  float s0 = 0.f, s1 = 0.f, s2 = 0.f, s3 = 0.f;
  for (int j = lane; j < DM; j += 64) {
    float xv = xr[j];
    float4 w = *(const float4*)(Wr + (size_t)j * NE);
    s0 += xv * w.x; s1 += xv * w.y; s2 += xv * w.z; s3 += xv * w.w;
  }
#pragma unroll
  for (int off = 32; off > 0; off >>= 1) {
    s0 += __shfl_xor(s0, off);
    s1 += __shfl_xor(s1, off);
    s2 += __shfl_xor(s2, off);
    s3 += __shfl_xor(s3, off);
  }
  if (lane == 0) {
    float l[NE] = {s0 + br[0], s1 + br[1], s2 + br[2], s3 + br[3]};
    int bi = 0; float bm = l[0];
#pragma unroll
    for (int e = 1; e < NE; e++) if (l[e] > bm) { bm = l[e]; bi = e; }
    float s = 0.f;
#pragma unroll
    for (int e = 0; e < NE; e++) s += __expf(l[e] - bm);
    top_idx[tok] = bi;
    top_w[tok] = 1.0f / s;
    atomicAdd(&counts[bi], 1);
  }
}

// ---------------- scan ----------------
__global__ void scan_kernel(const int* __restrict__ counts, int* __restrict__ offs,
                            int* __restrict__ cursors, int* __restrict__ tiles) {
  if (threadIdx.x != 0 || blockIdx.x != 0) return;
  int offv[NE + 1];
  offv[0] = 0;
  for (int e = 0; e < NE; e++) offv[e + 1] = offv[e] + counts[e];
  for (int e = 0; e <= NE; e++) offs[e] = offv[e];
  for (int e = 0; e < NE; e++) cursors[e] = offv[e];
  int nt = 0;
  for (int e = 0; e < NE; e++) {
    int c = counts[e];
    for (int s = 0; s < c; s += BM) {
      tiles[nt * 3 + 0] = e;
      tiles[nt * 3 + 1] = offv[e] + s;
      tiles[nt * 3 + 2] = (c - s < BM) ? (c - s) : BM;
      nt++;
    }
  }
  for (; nt < MAX_TILES; nt++) {
    tiles[nt * 3 + 0] = 0; tiles[nt * 3 + 1] = 0; tiles[nt * 3 + 2] = 0;
  }
}

// ---------------- scatter ----------------
__global__ __launch_bounds__(256) void scatter_kernel(
    const int* __restrict__ top_idx, int* __restrict__ cursors,
    int* __restrict__ sorted) {
  int t = blockIdx.x * blockDim.x + threadIdx.x;
  if (t >= T_TOK) return;
  int e = top_idx[t];
  int p = atomicAdd(&cursors[e], 1);
  sorted[p] = t;
}

// ---------------- gather_x ----------------
__global__ __launch_bounds__(256) void gather_x_kernel(
    const float* __restrict__ x, const int* __restrict__ sorted,
    unsigned short* __restrict__ xs) {
  const int row = blockIdx.x;
  const int t = threadIdx.x;
  unsigned short* orow = xs + (size_t)row * DM + (t << 3);
  if (row >= T_TOK) {
    short8 z = (short8){0,0,0,0,0,0,0,0};
    *(short8*)orow = z;
    return;
  }
  const float* irow = x + (size_t)sorted[row] * DM + (t << 3);
  float4 a = *(const float4*)irow;
  float4 b = *(const float4*)(irow + 4);
  short8 p;
  p[0] = (short)f2bf(a.x); p[1] = (short)f2bf(a.y);
  p[2] = (short)f2bf(a.z); p[3] = (short)f2bf(a.w);
  p[4] = (short)f2bf(b.x); p[5] = (short)f2bf(b.y);
  p[6] = (short)f2bf(b.z); p[7] = (short)f2bf(b.w);
  *(short8*)orow = p;
}

// ---------------- transpose+convert v2: fp32 [R][C] -> bf16 [C][R] ----------------
// Block: input rows r0..r0+255, cols c0..c0+63. Per-thread output = 128B contiguous.
// Output row runs grow to 512B (4 threads of same c). LDS 69.6 KB -> 2 blocks/CU.
__global__ __launch_bounds__(256) void transpose_cvt_kernel(
    const float* __restrict__ in, unsigned short* __restrict__ out, int R, int C) {
  __shared__ float tile[256][68];
  const size_t eo = (size_t)blockIdx.z * (size_t)R * (size_t)C;
  const float* inp = in + eo;
  unsigned short* outp = out + eo;
  const int r0 = blockIdx.y << 8, c0 = blockIdx.x << 6;
  const int t = threadIdx.x;
  const int lrow = t >> 4;          // 0..15
  const int lcol = (t & 15) << 2;   // 0,4,...,60
#pragma unroll
  for (int i = 0; i < 16; i++) {
    float4 v = *(const float4*)(inp + (size_t)(r0 + (i << 4) + lrow) * C + c0 + lcol);
    *(float4*)&tile[(i << 4) + lrow][lcol] = v;
  }
  __syncthreads();
  const int c = t >> 2;             // 0..63: output row (= input col)
  const int s = (t & 3) << 6;       // 0,64,128,192: segment start within the 256 r's
  unsigned short* po = outp + (size_t)(c0 + c) * R + r0 + s;
#pragma unroll
  for (int b = 0; b < 8; b++) {
    short8 pv;
#pragma unroll
    for (int i = 0; i < 8; i++) pv[i] = (short)f2bf(tile[s + (b << 3) + i][c]);
    *(short8*)(po + (b << 3)) = pv;
  }
}

// ---------------- gemm1 (bf16, 2-phase dbuf) — proven R5 form ----------------
// 256x128x64 tile, 8 waves (2M x 4N), wave tile 128x32 (g+u), LDS 128 KB, 1 blk/CU.
__global__ __launch_bounds__(512, 2) void gemm1_bf16_kernel(
    const unsigned short* __restrict__ xs, const unsigned short* __restrict__ wg,
    const unsigned short* __restrict__ wu, const int* __restrict__ tiles,
    unsigned short* __restrict__ hbuf) {
  const int slot = blockIdx.x;
  const int e = tiles[slot * 3 + 0];
  const int row0 = tiles[slot * 3 + 1];
  const int nvalid = tiles[slot * 3 + 2];
  if (nvalid == 0) return;
  const int n0 = blockIdx.y * GBN;

  __shared__ __align__(16) unsigned short As[2][BM * GBK];   // 64 KB
  __shared__ __align__(16) unsigned short Bg[2][GBN * GBK];  // 32 KB
  __shared__ __align__(16) unsigned short Bu[2][GBN * GBK];  // 32 KB

  const int t = threadIdx.x;
  const int w = t >> 6, lane = t & 63;
  const int l3 = lane >> 3;
  const int swz = (lane & 7) ^ l3;          // inverse-swizzled source granule
  const int lr = lane & 15;
  const int wm = w >> 2, wn = w & 3;

  const unsigned short* wge = wg + (size_t)e * DM * DF;
  const unsigned short* wue = wu + (size_t)e * DM * DF;

  // staging sources; wave role: w<4 -> A (8 chunks), w=4,5 -> Bg, w=6,7 -> Bu
  const unsigned short* sA = xs + (size_t)(row0 + (w << 6) + l3) * DM + (swz << 3);
  const unsigned short* sBg = wge + (size_t)(n0 + ((w - 4) << 6) + l3) * DM + (swz << 3);
  const unsigned short* sBu = wue + (size_t)(n0 + ((w - 6) << 6) + l3) * DM + (swz << 3);

  f32x4 accg[8][2], accu[8][2];
#pragma unroll
  for (int mi = 0; mi < 8; mi++)
#pragma unroll
    for (int ni = 0; ni < 2; ni++) {
      accg[mi][ni] = (f32x4){0.f, 0.f, 0.f, 0.f};
      accu[mi][ni] = (f32x4){0.f, 0.f, 0.f, 0.f};
    }

#define G1_STAGE(B, K0)                                                        \
  do {                                                                         \
    if (w < 4) {                                                               \
      unsigned short* d = &As[B][(w << 6) << 6];                               \
      _Pragma("unroll")                                                        \
      for (int j = 0; j < 8; j++)                                              \
        gld_lds16(sA + (size_t)(j << 3) * DM + (K0), d + (j << 9));            \
    } else if (w < 6) {                                                        \
      unsigned short* d = &Bg[B][((w - 4) << 6) << 6];                         \
      _Pragma("unroll")                                                        \
      for (int j = 0; j < 8; j++)                                              \
        gld_lds16(sBg + (size_t)(j << 3) * DM + (K0), d + (j << 9));           \
    } else {                                                                   \
      unsigned short* d = &Bu[B][((w - 6) << 6) << 6];                         \
      _Pragma("unroll")                                                        \
      for (int j = 0; j < 8; j++)                                              \
        gld_lds16(sBu + (size_t)(j << 3) * DM + (K0), d + (j << 9));           \
    }                                                                          \
  } while (0)

#define G1_COMPUTE(B)                                                          \
  do {                                                                         \
    _Pragma("unroll")                                                          \
    for (int h = 0; h < 2; h++) {                                              \
      const int gq = (h << 2) + (lane >> 4);                                   \
      const int g = gq ^ (lr & 7);                                             \
      short8 af[8], bgf[2], buf2[2];                                           \
      _Pragma("unroll")                                                        \
      for (int mi = 0; mi < 8; mi++) {                                         \
        int row = (wm << 7) + (mi << 4) + lr;                                  \
        af[mi] = *(const short8*)&As[B][(row << 6) + (g << 3)];                \
      }                                                                        \
      _Pragma("unroll")                                                        \
      for (int ni = 0; ni < 2; ni++) {                                         \
        int row = (wn << 5) + (ni << 4) + lr;                                  \
        bgf[ni]  = *(const short8*)&Bg[B][(row << 6) + (g << 3)];              \
        buf2[ni] = *(const short8*)&Bu[B][(row << 6) + (g << 3)];              \
      }                                                                        \
      _Pragma("unroll")                                                        \
      for (int mi = 0; mi < 8; mi++)                                           \
        _Pragma("unroll")                                                      \
        for (int ni = 0; ni < 2; ni++) {                                       \
          accg[mi][ni] = __builtin_amdgcn_mfma_f32_16x16x32_bf16(              \
              af[mi], bgf[ni], accg[mi][ni], 0, 0, 0);                         \
          accu[mi][ni] = __builtin_amdgcn_mfma_f32_16x16x32_bf16(              \
              af[mi], buf2[ni], accu[mi][ni], 0, 0, 0);                        \
        }                                                                      \
    }                                                                          \
  } while (0)

  const int NK = DM / GBK;  // 32
  int cur = 0;
  G1_STAGE(0, 0);
  __syncthreads();
  for (int kt = 0; kt < NK - 1; ++kt) {
    G1_STAGE(cur ^ 1, (kt + 1) * GBK);   // prefetch next tile (in flight across compute)
    G1_COMPUTE(cur);
    __syncthreads();                     // drains vmcnt after a full MFMA phase
    cur ^= 1;
  }
  G1_COMPUTE(cur);

  const int l4 = (lane >> 4) << 2;
#pragma unroll
  for (int mi = 0; mi < 8; mi++) {
#pragma unroll
    for (int r = 0; r < 4; r++) {
      int lrow = (wm << 7) + (mi << 4) + l4 + r;
      if (lrow < nvalid) {
        size_t base = (size_t)(row0 + lrow) * DF + n0 + (wn << 5) + lr;
#pragma unroll
        for (int ni = 0; ni < 2; ni++) {
          float gv = accg[mi][ni][r];
          float uv = accu[mi][ni][r];
          float hv = (gv / (1.f + __expf(-gv))) * uv;
          hbuf[base + (ni << 4)] = f2bf(hv);
        }
      }
    }
  }
#undef G1_STAGE
#undef G1_COMPUTE
}

// ---------------- gemm2 (bf16, 2-phase dbuf, G2BK=32) — proven R5 form ----------------
__global__ __launch_bounds__(512, 4) void gemm2_bf16_kernel(
    const unsigned short* __restrict__ hbuf, const unsigned short* __restrict__ wd,
    const int* __restrict__ tiles, const int* __restrict__ sorted,
    const float* __restrict__ topw, float* __restrict__ out) {
  const int slot = blockIdx.x;
  const int e = tiles[slot * 3 + 0];
  const int row0 = tiles[slot * 3 + 1];
  const int nvalid = tiles[slot * 3 + 2];
  if (nvalid == 0) return;
  const int n0 = blockIdx.y * GBN;

  __shared__ __align__(16) unsigned short As[2][BM * G2BK];   // 2 x 16 KB
  __shared__ __align__(16) unsigned short Bs[2][GBN * G2BK];  // 2 x 8 KB

  const int t = threadIdx.x;
  const int w = t >> 6, lane = t & 63;
  const int lr = lane & 15;
  const int wm = w >> 2, wn = w & 3;

  const int srow = lane >> 2;
  const int sg = (lane & 3) ^ ((lane >> 3) & 3);

  const unsigned short* wde = wd + (size_t)e * DM * DF;
  const unsigned short* sA = hbuf + (size_t)(row0 + (w << 6) + srow) * DF + (sg << 3);
  const unsigned short* sB = wde + (size_t)(n0 + ((w - 4) << 5) + srow) * DF + (sg << 3);

  f32x4 acc[8][2];
#pragma unroll
  for (int mi = 0; mi < 8; mi++)
#pragma unroll
    for (int ni = 0; ni < 2; ni++) acc[mi][ni] = (f32x4){0.f, 0.f, 0.f, 0.f};

#define G2_STAGE(B_, K0)                                                       \
  do {                                                                         \
    if (w < 4) {                                                               \
      _Pragma("unroll")                                                        \
      for (int j = 0; j < 4; j++)                                              \
        gld_lds16(sA + (size_t)(j << 4) * DF + (K0),                           \
                  &As[B_][((w << 2) + j) << 9]);                               \
    } else {                                                                   \
      _Pragma("unroll")                                                        \
      for (int j = 0; j < 2; j++)                                              \
        gld_lds16(sB + (size_t)(j << 4) * DF + (K0),                           \
                  &Bs[B_][(((w - 4) << 1) + j) << 9]);                         \
    }                                                                          \
  } while (0)

#define G2_COMPUTE(B_)                                                         \
  do {                                                                         \
    const int q = lane >> 4;                                                   \
    const int p = q ^ ((lr >> 1) & 3);                                         \
    short8 af[8], bf2[2];                                                      \
    _Pragma("unroll")                                                          \
    for (int mi = 0; mi < 8; mi++) {                                           \
      int row = (wm << 7) + (mi << 4) + lr;                                    \
      af[mi] = *(const short8*)&As[B_][(row << 5) + (p << 3)];                 \
    }                                                                          \
    _Pragma("unroll")                                                          \
    for (int ni = 0; ni < 2; ni++) {                                           \
      int row = (wn << 5) + (ni << 4) + lr;                                    \
      bf2[ni] = *(const short8*)&Bs[B_][(row << 5) + (p << 3)];                \
    }                                                                          \
    _Pragma("unroll")                                                          \
    for (int mi = 0; mi < 8; mi++)                                             \
      _Pragma("unroll")                                                        \
      for (int ni = 0; ni < 2; ni++)                                           \
        acc[mi][ni] = __builtin_amdgcn_mfma_f32_16x16x32_bf16(                 \
            af[mi], bf2[ni], acc[mi][ni], 0, 0, 0);                            \
  } while (0)

  const int NK = DF / G2BK;  // 256
  int cur = 0;
  G2_STAGE(0, 0);
  __syncthreads();
  for (int kt = 0; kt < NK - 1; ++kt) {
    G2_STAGE(cur ^ 1, (kt + 1) * G2BK);
    G2_COMPUTE(cur);
    __syncthreads();
    cur ^= 1;
  }
  G2_COMPUTE(cur);

  const int l4 = (lane >> 4) << 2;
#pragma unroll
  for (int mi = 0; mi < 8; mi++) {
#pragma unroll
    for (int r = 0; r < 4; r++) {
      int lrow = (wm << 7) + (mi << 4) + l4 + r;
      if (lrow < nvalid) {
        int tok = sorted[row0 + lrow];
        float wv = topw[tok];
        size_t base = (size_t)tok * DM + n0 + (wn << 5) + lr;
#pragma unroll
        for (int ni = 0; ni < 2; ni++)
          out[base + (ni << 4)] = acc[mi][ni][r] * wv;
      }
    }
  }
#undef G2_STAGE
#undef G2_COMPUTE
}

// ================= fallback fp32-weight kernels =================
__global__ __launch_bounds__(512, 4) void gemm1_f32_kernel(
    const float* __restrict__ x, const float* __restrict__ Wg,
    const float* __restrict__ Wu, const int* __restrict__ tiles,
    const int* __restrict__ sorted, unsigned short* __restrict__ hbuf) {
  const int slot = blockIdx.x;
  const int e = tiles[slot * 3 + 0];
  const int row0 = tiles[slot * 3 + 1];
  const int nvalid = tiles[slot * 3 + 2];
  if (nvalid == 0) return;
  const int n0 = blockIdx.y * BN;

  __shared__ __align__(16) unsigned short As[BM][LDK];
  __shared__ __align__(16) unsigned short Bg[BN][LDK];
  __shared__ __align__(16) unsigned short Bu[BN][LDK];

  const int t = threadIdx.x;
  const int arow = t >> 1;
  const int ah = (t & 1) << 4;
  const int atok = (arow < nvalid) ? sorted[row0 + arow] : -1;
  const float* __restrict__ xrow = x + (size_t)(atok >= 0 ? atok : 0) * DM;
  const int bn = t & 63;
  const int bkq = (t >> 6) << 2;

  const size_t eo = (size_t)e * DM * DF;
  const float* __restrict__ Wge = Wg + eo;
  const float* __restrict__ Wue = Wu + eo;

  const int wv = t >> 6, lane = t & 63;
  const int wrow = (wv >> 1) << 6, wcol = (wv & 1) << 5;
  const int lr = lane & 15, lk = (lane >> 4) << 3;

  f32x4 accg[4][2], accu[4][2];
#pragma unroll
  for (int mi = 0; mi < 4; mi++)
#pragma unroll
    for (int ni = 0; ni < 2; ni++) {
      accg[mi][ni] = (f32x4){0.f, 0.f, 0.f, 0.f};
      accu[mi][ni] = (f32x4){0.f, 0.f, 0.f, 0.f};
    }

  for (int k0 = 0; k0 < DM; k0 += BKO) {
#pragma unroll
    for (int j = 0; j < 4; j++) {
      float4 v = make_float4(0.f, 0.f, 0.f, 0.f);
      if (atok >= 0) v = *(const float4*)(xrow + k0 + ah + (j << 2));
      ushort4 pv;
      pv.x = f2bf(v.x); pv.y = f2bf(v.y); pv.z = f2bf(v.z); pv.w = f2bf(v.w);
      *(ushort4*)&As[arow][ah + (j << 2)] = pv;
    }
    {
      const float* pg = Wge + (size_t)(k0 + bkq) * DF + n0 + bn;
      const float* pu = Wue + (size_t)(k0 + bkq) * DF + n0 + bn;
      ushort4 vg, vu;
      vg.x = f2bf(pg[0]);              vu.x = f2bf(pu[0]);
      vg.y = f2bf(pg[(size_t)DF]);     vu.y = f2bf(pu[(size_t)DF]);
      vg.z = f2bf(pg[(size_t)2 * DF]); vu.z = f2bf(pu[(size_t)2 * DF]);
      vg.w = f2bf(pg[(size_t)3 * DF]); vu.w = f2bf(pu[(size_t)3 * DF]);
      *(ushort4*)&Bg[bn][bkq] = vg;
      *(ushort4*)&Bu[bn][bkq] = vu;
    }
    __syncthreads();

    short8 af[4], bgf[2], buf2[2];
#pragma unroll
    for (int mi = 0; mi < 4; mi++)
      af[mi] = *(const short8*)&As[wrow + (mi << 4) + lr][lk];
#pragma unroll
    for (int ni = 0; ni < 2; ni++) {
      bgf[ni]  = *(const short8*)&Bg[wcol + (ni << 4) + lr][lk];
      buf2[ni] = *(const short8*)&Bu[wcol + (ni << 4) + lr][lk];
    }
#pragma unroll
    for (int mi = 0; mi < 4; mi++)
#pragma unroll
      for (int ni = 0; ni < 2; ni++) {
        accg[mi][ni] = __builtin_amdgcn_mfma_f32_16x16x32_bf16(af[mi], bgf[ni], accg[mi][ni], 0, 0, 0);
        accu[mi][ni] = __builtin_amdgcn_mfma_f32_16x16x32_bf16(af[mi], buf2[ni], accu[mi][ni], 0, 0, 0);
      }
    __syncthreads();
  }

  const int l4 = (lane >> 4) << 2;
#pragma unroll
  for (int mi = 0; mi < 4; mi++) {
#pragma unroll
    for (int r = 0; r < 4; r++) {
      int lrow = wrow + (mi << 4) + l4 + r;
      if (lrow < nvalid) {
        size_t base = (size_t)(row0 + lrow) * DF + n0 + wcol + lr;
#pragma unroll
        for (int ni = 0; ni < 2; ni++) {
          float g = accg[mi][ni][r];
          float u = accu[mi][ni][r];
          float hv = (g / (1.f + __expf(-g))) * u;
          hbuf[base + (ni << 4)] = f2bf(hv);
        }
      }
    }
  }
}

__global__ __launch_bounds__(512, 4) void gemm2_f32_kernel(
    const unsigned short* __restrict__ hbuf, const float* __restrict__ Wd,
    const int* __restrict__ tiles, const int* __restrict__ sorted,
    const float* __restrict__ topw, float* __restrict__ out) {
  const int slot = blockIdx.x;
  const int e = tiles[slot * 3 + 0];
  const int row0 = tiles[slot * 3 + 1];
  const int nvalid = tiles[slot * 3 + 2];
  if (nvalid == 0) return;
  const int n0 = blockIdx.y * BN;

  __shared__ __align__(16) unsigned short As[BM][LDK];
  __shared__ __align__(16) unsigned short Bs[BN][LDK];

  const int t = threadIdx.x;
  const int arow = t >> 1;
  const int ah = (t & 1) << 4;
  const int bn = t & 63;
  const int bkq = (t >> 6) << 2;
  const float* __restrict__ Wde = Wd + (size_t)e * DF * DM;

  const int wv = t >> 6, lane = t & 63;
  const int wrow = (wv >> 1) << 6, wcol = (wv & 1) << 5;
  const int lr = lane & 15, lk = (lane >> 4) << 3;

  f32x4 acc[4][2];
#pragma unroll
  for (int mi = 0; mi < 4; mi++)
#pragma unroll
    for (int ni = 0; ni < 2; ni++) acc[mi][ni] = (f32x4){0.f, 0.f, 0.f, 0.f};

  const unsigned short* __restrict__ hrow =
      hbuf + (size_t)(row0 + (arow < nvalid ? arow : 0)) * DF;

  for (int k0 = 0; k0 < DF; k0 += BKO) {
    {
      short8 v0 = (short8){0,0,0,0,0,0,0,0}, v1 = v0;
      if (arow < nvalid) {
        v0 = *(const short8*)(hrow + k0 + ah);
        v1 = *(const short8*)(hrow + k0 + ah + 8);
      }
      *(short8*)&As[arow][ah] = v0;
      *(short8*)&As[arow][ah + 8] = v1;
    }
    {
      const float* pd = Wde + (size_t)(k0 + bkq) * DM + n0 + bn;
      ushort4 vd;
      vd.x = f2bf(pd[0]);
      vd.y = f2bf(pd[(size_t)DM]);
      vd.z = f2bf(pd[(size_t)2 * DM]);
      vd.w = f2bf(pd[(size_t)3 * DM]);
      *(ushort4*)&Bs[bn][bkq] = vd;
    }
    __syncthreads();

    short8 af[4], bf2[2];
#pragma unroll
    for (int mi = 0; mi < 4; mi++)
      af[mi] = *(const short8*)&As[wrow + (mi << 4) + lr][lk];
#pragma unroll
    for (int ni = 0; ni < 2; ni++)
      bf2[ni] = *(const short8*)&Bs[wcol + (ni << 4) + lr][lk];
#pragma unroll
    for (int mi = 0; mi < 4; mi++)
#pragma unroll
      for (int ni = 0; ni < 2; ni++)
        acc[mi][ni] = __builtin_amdgcn_mfma_f32_16x16x32_bf16(af[mi], bf2[ni], acc[mi][ni], 0, 0, 0);
    __syncthreads();
  }

  const int l4 = (lane >> 4) << 2;
#pragma unroll
  for (int mi = 0; mi < 4; mi++) {
#pragma unroll
    for (int r = 0; r < 4; r++) {
      int lrow = wrow + (mi << 4) + l4 + r;
      if (lrow < nvalid) {
        int tok = sorted[row0 + lrow];
        float w = topw[tok];
        size_t base = (size_t)tok * DM + n0 + wcol + lr;
#pragma unroll
        for (int ni = 0; ni < 2; ni++)
          out[base + (ni << 4)] = acc[mi][ni][r] * w;
      }
    }
  }
}

extern "C" void kernel_launch(void* const* d_in, const int* in_sizes, int n_in,
                              void* d_out, int out_size, void* d_ws, size_t ws_size,
                              hipStream_t stream) {
  const float* x  = (const float*)d_in[0];
  const float* Wr = (const float*)d_in[1];
  const float* br = (const float*)d_in[2];
  const float* Wg = (const float*)d_in[3];
  const float* Wu = (const float*)d_in[4];
  const float* Wd = (const float*)d_in[5];
  float* out = (float*)d_out;

  const size_t XS_ELEMS = (size_t)(T_TOK + PADROWS) * DM;
  const size_t HB_ELEMS = (size_t)(T_TOK + PADROWS) * DF;
  const size_t W_ELEMS  = (size_t)NE * DM * DF;
  const size_t NEED = (XS_ELEMS + HB_ELEMS + 3 * W_ELEMS) * 2 + (1 << 20);

  if (ws_size >= NEED) {
    // ---------- bf16 fast path ----------
    unsigned short* xs = (unsigned short*)d_ws;
    unsigned short* hb = xs + XS_ELEMS;
    unsigned short* wg = hb + HB_ELEMS;
    unsigned short* wu = wg + W_ELEMS;
    unsigned short* wd = wu + W_ELEMS;
    int* meta = (int*)(wd + W_ELEMS);
    int* top_idx = meta;
    int* sorted  = meta + 4096;
    int* counts  = meta + 8192;
    int* offs    = meta + 8196;
    int* cursors = meta + 8201;
    int* tiles   = meta + 8208;
    float* topw  = (float*)(meta + 8320);

    hipMemsetAsync(counts, 0, NE * sizeof(int), stream);
    router_kernel<<<dim3((T_TOK * 64) / 256), 256, 0, stream>>>(x, Wr, br, top_idx, topw, counts);
    scan_kernel<<<1, 1, 0, stream>>>(counts, offs, cursors, tiles);
    scatter_kernel<<<dim3(T_TOK / 256), 256, 0, stream>>>(top_idx, cursors, sorted);
    gather_x_kernel<<<dim3(T_TOK + PADROWS), 256, 0, stream>>>(x, sorted, xs);
    // Wg/Wu: [E][DM][DF] -> [E][DF][DM]; Wd: [E][DF][DM] -> [E][DM][DF]
    transpose_cvt_kernel<<<dim3(DF / 64, DM / 256, NE), 256, 0, stream>>>(Wg, wg, DM, DF);
    transpose_cvt_kernel<<<dim3(DF / 64, DM / 256, NE), 256, 0, stream>>>(Wu, wu, DM, DF);
    transpose_cvt_kernel<<<dim3(DM / 64, DF / 256, NE), 256, 0, stream>>>(Wd, wd, DF, DM);
    gemm1_bf16_kernel<<<dim3(MAX_TILES, DF / GBN), 512, 0, stream>>>(xs, wg, wu, tiles, hb);
    gemm2_bf16_kernel<<<dim3(MAX_TILES, DM / GBN), 512, 0, stream>>>(hb, wd, tiles, sorted, topw, out);
  } else {
    // ---------- fallback path ----------
    const size_t H_BYTES = (size_t)T_TOK * DF * 2;
    unsigned short* hbuf = (unsigned short*)d_ws;
    int* meta = (int*)((char*)d_ws + H_BYTES);
    int* top_idx = meta;
    int* sorted  = meta + 4096;
    int* counts  = meta + 8192;
    int* offs    = meta + 8196;
    int* cursors = meta + 8201;
    int* tiles   = meta + 8208;
    float* topw  = (float*)(meta + 8320);

    hipMemsetAsync(counts, 0, NE * sizeof(int), stream);
    router_kernel<<<dim3((T_TOK * 64) / 256), 256, 0, stream>>>(x, Wr, br, top_idx, topw, counts);
    scan_kernel<<<1, 1, 0, stream>>>(counts, offs, cursors, tiles);
    scatter_kernel<<<dim3(T_TOK / 256), 256, 0, stream>>>(top_idx, cursors, sorted);
    gemm1_f32_kernel<<<dim3(MAX_TILES, DF / BN), 512, 0, stream>>>(x, Wg, Wu, tiles, sorted, hbuf);
    gemm2_f32_kernel<<<dim3(MAX_TILES, DM / BN), 512, 0, stream>>>(hbuf, Wd, tiles, sorted, topw, out);
  }
}

// Round 10
// 897.920 us; speedup vs baseline: 1.0859x; 1.0859x over previous
//
#include <hip/hip_runtime.h>

#define T_TOK 4096
#define DM 2048
#define DF 8192
#define NE 4
#define BM 256
#define BN 64        // fallback geometry
#define GBN 128      // new-path N tile
#define GBK 64       // gemm1 K step
#define G2BK 32      // gemm2 K step (48 KB LDS -> 2 blocks/CU)
#define BKO 32
#define MAX_TILES 20
#define PADROWS 256
#define LDK (BKO + 8)

typedef __attribute__((ext_vector_type(8))) short short8;
typedef __attribute__((ext_vector_type(4))) float f32x4;

__device__ __forceinline__ unsigned short f2bf(float f) {
  unsigned int u = __float_as_uint(f);
  u += 0x7fffu + ((u >> 16) & 1u);   // round-to-nearest-even
  return (unsigned short)(u >> 16);
}

// async global->LDS, 16B/lane; LDS base wave-uniform (HW: base + lane*16)
__device__ __forceinline__ void gld_lds16(const unsigned short* g, unsigned short* l) {
  __builtin_amdgcn_global_load_lds(
      (const __attribute__((address_space(1))) unsigned int*)g,
      (__attribute__((address_space(3))) unsigned int*)l, 16, 0, 0);
}

// ---------------- router ----------------
__global__ __launch_bounds__(256) void router_kernel(
    const float* __restrict__ x, const float* __restrict__ Wr,
    const float* __restrict__ br, int* __restrict__ top_idx,
    float* __restrict__ top_w, int* __restrict__ counts) {
  int tok = (blockIdx.x * blockDim.x + threadIdx.x) >> 6;
  int lane = threadIdx.x & 63;
  if (tok >= T_TOK) return;
  const float* xr = x + (size_t)tok * DM;
  float s0 = 0.f, s1 = 0.f, s2 = 0.f, s3 = 0.f;
  for (int j = lane; j < DM; j += 64) {
    float xv = xr[j];
    float4 w = *(const float4*)(Wr + (size_t)j * NE);
    s0 += xv * w.x; s1 += xv * w.y; s2 += xv * w.z; s3 += xv * w.w;
  }
#pragma unroll
  for (int off = 32; off > 0; off >>= 1) {
    s0 += __shfl_xor(s0, off);
    s1 += __shfl_xor(s1, off);
    s2 += __shfl_xor(s2, off);
    s3 += __shfl_xor(s3, off);
  }
  if (lane == 0) {
    float l[NE] = {s0 + br[0], s1 + br[1], s2 + br[2], s3 + br[3]};
    int bi = 0; float bm = l[0];
#pragma unroll
    for (int e = 1; e < NE; e++) if (l[e] > bm) { bm = l[e]; bi = e; }
    float s = 0.f;
#pragma unroll
    for (int e = 0; e < NE; e++) s += __expf(l[e] - bm);
    top_idx[tok] = bi;
    top_w[tok] = 1.0f / s;
    atomicAdd(&counts[bi], 1);
  }
}

// ---------------- scan ----------------
__global__ void scan_kernel(const int* __restrict__ counts, int* __restrict__ offs,
                            int* __restrict__ cursors, int* __restrict__ tiles) {
  if (threadIdx.x != 0 || blockIdx.x != 0) return;
  int offv[NE + 1];
  offv[0] = 0;
  for (int e = 0; e < NE; e++) offv[e + 1] = offv[e] + counts[e];
  for (int e = 0; e <= NE; e++) offs[e] = offv[e];
  for (int e = 0; e < NE; e++) cursors[e] = offv[e];
  int nt = 0;
  for (int e = 0; e < NE; e++) {
    int c = counts[e];
    for (int s = 0; s < c; s += BM) {
      tiles[nt * 3 + 0] = e;
      tiles[nt * 3 + 1] = offv[e] + s;
      tiles[nt * 3 + 2] = (c - s < BM) ? (c - s) : BM;
      nt++;
    }
  }
  for (; nt < MAX_TILES; nt++) {
    tiles[nt * 3 + 0] = 0; tiles[nt * 3 + 1] = 0; tiles[nt * 3 + 2] = 0;
  }
}

// ---------------- scatter ----------------
__global__ __launch_bounds__(256) void scatter_kernel(
    const int* __restrict__ top_idx, int* __restrict__ cursors,
    int* __restrict__ sorted) {
  int t = blockIdx.x * blockDim.x + threadIdx.x;
  if (t >= T_TOK) return;
  int e = top_idx[t];
  int p = atomicAdd(&cursors[e], 1);
  sorted[p] = t;
}

// ---------------- gather_x ----------------
__global__ __launch_bounds__(256) void gather_x_kernel(
    const float* __restrict__ x, const int* __restrict__ sorted,
    unsigned short* __restrict__ xs) {
  const int row = blockIdx.x;
  const int t = threadIdx.x;
  unsigned short* orow = xs + (size_t)row * DM + (t << 3);
  if (row >= T_TOK) {
    short8 z = (short8){0,0,0,0,0,0,0,0};
    *(short8*)orow = z;
    return;
  }
  const float* irow = x + (size_t)sorted[row] * DM + (t << 3);
  float4 a = *(const float4*)irow;
  float4 b = *(const float4*)(irow + 4);
  short8 p;
  p[0] = (short)f2bf(a.x); p[1] = (short)f2bf(a.y);
  p[2] = (short)f2bf(a.z); p[3] = (short)f2bf(a.w);
  p[4] = (short)f2bf(b.x); p[5] = (short)f2bf(b.y);
  p[6] = (short)f2bf(b.z); p[7] = (short)f2bf(b.w);
  *(short8*)orow = p;
}

// ---------------- transpose+convert: fp32 [R][C] -> bf16 [C][R] ----------------
// v1 geometry (64x64 tile, ~8 blocks/CU TLP) + stride-65 LDS: bank = (row+c)%32
// -> column reads are 2-way (free) instead of 8-way with stride 68.
__global__ __launch_bounds__(256) void transpose_cvt_kernel(
    const float* __restrict__ in, unsigned short* __restrict__ out, int R, int C) {
  __shared__ float tile[64][65];
  const size_t eo = (size_t)blockIdx.z * (size_t)R * (size_t)C;
  const float* inp = in + eo;
  unsigned short* outp = out + eo;
  const int r0 = blockIdx.y << 6, c0 = blockIdx.x << 6;
  const int t = threadIdx.x;
  const int lrow = t >> 4, lcol = (t & 15) << 2;
#pragma unroll
  for (int i = 0; i < 4; i++) {
    float4 v = *(const float4*)(inp + (size_t)(r0 + (i << 4) + lrow) * C + c0 + lcol);
    *(float4*)&tile[(i << 4) + lrow][lcol] = v;
  }
  __syncthreads();
  const int gg = t & 7, cc = t >> 3;
#pragma unroll
  for (int cp = 0; cp < 2; cp++) {
    int c = cc + (cp << 5);
    short8 pv;
#pragma unroll
    for (int i = 0; i < 8; i++) pv[i] = (short)f2bf(tile[(gg << 3) + i][c]);
    *(short8*)(outp + (size_t)(c0 + c) * R + r0 + (gg << 3)) = pv;
  }
}

// ---------------- gemm1 (bf16, 2-phase dbuf) — proven R5 form ----------------
// 256x128x64 tile, 8 waves (2M x 4N), wave tile 128x32 (g+u), LDS 128 KB, 1 blk/CU.
__global__ __launch_bounds__(512, 2) void gemm1_bf16_kernel(
    const unsigned short* __restrict__ xs, const unsigned short* __restrict__ wg,
    const unsigned short* __restrict__ wu, const int* __restrict__ tiles,
    unsigned short* __restrict__ hbuf) {
  const int slot = blockIdx.x;
  const int e = tiles[slot * 3 + 0];
  const int row0 = tiles[slot * 3 + 1];
  const int nvalid = tiles[slot * 3 + 2];
  if (nvalid == 0) return;
  const int n0 = blockIdx.y * GBN;

  __shared__ __align__(16) unsigned short As[2][BM * GBK];   // 64 KB
  __shared__ __align__(16) unsigned short Bg[2][GBN * GBK];  // 32 KB
  __shared__ __align__(16) unsigned short Bu[2][GBN * GBK];  // 32 KB

  const int t = threadIdx.x;
  const int w = t >> 6, lane = t & 63;
  const int l3 = lane >> 3;
  const int swz = (lane & 7) ^ l3;          // inverse-swizzled source granule
  const int lr = lane & 15;
  const int wm = w >> 2, wn = w & 3;

  const unsigned short* wge = wg + (size_t)e * DM * DF;
  const unsigned short* wue = wu + (size_t)e * DM * DF;

  // staging sources; wave role: w<4 -> A (8 chunks), w=4,5 -> Bg, w=6,7 -> Bu
  const unsigned short* sA = xs + (size_t)(row0 + (w << 6) + l3) * DM + (swz << 3);
  const unsigned short* sBg = wge + (size_t)(n0 + ((w - 4) << 6) + l3) * DM + (swz << 3);
  const unsigned short* sBu = wue + (size_t)(n0 + ((w - 6) << 6) + l3) * DM + (swz << 3);

  f32x4 accg[8][2], accu[8][2];
#pragma unroll
  for (int mi = 0; mi < 8; mi++)
#pragma unroll
    for (int ni = 0; ni < 2; ni++) {
      accg[mi][ni] = (f32x4){0.f, 0.f, 0.f, 0.f};
      accu[mi][ni] = (f32x4){0.f, 0.f, 0.f, 0.f};
    }

#define G1_STAGE(B, K0)                                                        \
  do {                                                                         \
    if (w < 4) {                                                               \
      unsigned short* d = &As[B][(w << 6) << 6];                               \
      _Pragma("unroll")                                                        \
      for (int j = 0; j < 8; j++)                                              \
        gld_lds16(sA + (size_t)(j << 3) * DM + (K0), d + (j << 9));            \
    } else if (w < 6) {                                                        \
      unsigned short* d = &Bg[B][((w - 4) << 6) << 6];                         \
      _Pragma("unroll")                                                        \
      for (int j = 0; j < 8; j++)                                              \
        gld_lds16(sBg + (size_t)(j << 3) * DM + (K0), d + (j << 9));           \
    } else {                                                                   \
      unsigned short* d = &Bu[B][((w - 6) << 6) << 6];                         \
      _Pragma("unroll")                                                        \
      for (int j = 0; j < 8; j++)                                              \
        gld_lds16(sBu + (size_t)(j << 3) * DM + (K0), d + (j << 9));           \
    }                                                                          \
  } while (0)

#define G1_COMPUTE(B)                                                          \
  do {                                                                         \
    _Pragma("unroll")                                                          \
    for (int h = 0; h < 2; h++) {                                              \
      const int gq = (h << 2) + (lane >> 4);                                   \
      const int g = gq ^ (lr & 7);                                             \
      short8 af[8], bgf[2], buf2[2];                                           \
      _Pragma("unroll")                                                        \
      for (int mi = 0; mi < 8; mi++) {                                         \
        int row = (wm << 7) + (mi << 4) + lr;                                  \
        af[mi] = *(const short8*)&As[B][(row << 6) + (g << 3)];                \
      }                                                                        \
      _Pragma("unroll")                                                        \
      for (int ni = 0; ni < 2; ni++) {                                         \
        int row = (wn << 5) + (ni << 4) + lr;                                  \
        bgf[ni]  = *(const short8*)&Bg[B][(row << 6) + (g << 3)];              \
        buf2[ni] = *(const short8*)&Bu[B][(row << 6) + (g << 3)];              \
      }                                                                        \
      _Pragma("unroll")                                                        \
      for (int mi = 0; mi < 8; mi++)                                           \
        _Pragma("unroll")                                                      \
        for (int ni = 0; ni < 2; ni++) {                                       \
          accg[mi][ni] = __builtin_amdgcn_mfma_f32_16x16x32_bf16(              \
              af[mi], bgf[ni], accg[mi][ni], 0, 0, 0);                         \
          accu[mi][ni] = __builtin_amdgcn_mfma_f32_16x16x32_bf16(              \
              af[mi], buf2[ni], accu[mi][ni], 0, 0, 0);                        \
        }                                                                      \
    }                                                                          \
  } while (0)

  const int NK = DM / GBK;  // 32
  int cur = 0;
  G1_STAGE(0, 0);
  __syncthreads();
  for (int kt = 0; kt < NK - 1; ++kt) {
    G1_STAGE(cur ^ 1, (kt + 1) * GBK);   // prefetch next tile (in flight across compute)
    G1_COMPUTE(cur);
    __syncthreads();                     // drains vmcnt after a full MFMA phase
    cur ^= 1;
  }
  G1_COMPUTE(cur);

  const int l4 = (lane >> 4) << 2;
#pragma unroll
  for (int mi = 0; mi < 8; mi++) {
#pragma unroll
    for (int r = 0; r < 4; r++) {
      int lrow = (wm << 7) + (mi << 4) + l4 + r;
      if (lrow < nvalid) {
        size_t base = (size_t)(row0 + lrow) * DF + n0 + (wn << 5) + lr;
#pragma unroll
        for (int ni = 0; ni < 2; ni++) {
          float gv = accg[mi][ni][r];
          float uv = accu[mi][ni][r];
          float hv = (gv / (1.f + __expf(-gv))) * uv;
          hbuf[base + (ni << 4)] = f2bf(hv);
        }
      }
    }
  }
#undef G1_STAGE
#undef G1_COMPUTE
}

// ---------------- gemm2 (bf16, 2-phase dbuf, G2BK=32) — proven R5 form ----------------
__global__ __launch_bounds__(512, 4) void gemm2_bf16_kernel(
    const unsigned short* __restrict__ hbuf, const unsigned short* __restrict__ wd,
    const int* __restrict__ tiles, const int* __restrict__ sorted,
    const float* __restrict__ topw, float* __restrict__ out) {
  const int slot = blockIdx.x;
  const int e = tiles[slot * 3 + 0];
  const int row0 = tiles[slot * 3 + 1];
  const int nvalid = tiles[slot * 3 + 2];
  if (nvalid == 0) return;
  const int n0 = blockIdx.y * GBN;

  __shared__ __align__(16) unsigned short As[2][BM * G2BK];   // 2 x 16 KB
  __shared__ __align__(16) unsigned short Bs[2][GBN * G2BK];  // 2 x 8 KB

  const int t = threadIdx.x;
  const int w = t >> 6, lane = t & 63;
  const int lr = lane & 15;
  const int wm = w >> 2, wn = w & 3;

  const int srow = lane >> 2;
  const int sg = (lane & 3) ^ ((lane >> 3) & 3);

  const unsigned short* wde = wd + (size_t)e * DM * DF;
  const unsigned short* sA = hbuf + (size_t)(row0 + (w << 6) + srow) * DF + (sg << 3);
  const unsigned short* sB = wde + (size_t)(n0 + ((w - 4) << 5) + srow) * DF + (sg << 3);

  f32x4 acc[8][2];
#pragma unroll
  for (int mi = 0; mi < 8; mi++)
#pragma unroll
    for (int ni = 0; ni < 2; ni++) acc[mi][ni] = (f32x4){0.f, 0.f, 0.f, 0.f};

#define G2_STAGE(B_, K0)                                                       \
  do {                                                                         \
    if (w < 4) {                                                               \
      _Pragma("unroll")                                                        \
      for (int j = 0; j < 4; j++)                                              \
        gld_lds16(sA + (size_t)(j << 4) * DF + (K0),                           \
                  &As[B_][((w << 2) + j) << 9]);                               \
    } else {                                                                   \
      _Pragma("unroll")                                                        \
      for (int j = 0; j < 2; j++)                                              \
        gld_lds16(sB + (size_t)(j << 4) * DF + (K0),                           \
                  &Bs[B_][(((w - 4) << 1) + j) << 9]);                         \
    }                                                                          \
  } while (0)

#define G2_COMPUTE(B_)                                                         \
  do {                                                                         \
    const int q = lane >> 4;                                                   \
    const int p = q ^ ((lr >> 1) & 3);                                         \
    short8 af[8], bf2[2];                                                      \
    _Pragma("unroll")                                                          \
    for (int mi = 0; mi < 8; mi++) {                                           \
      int row = (wm << 7) + (mi << 4) + lr;                                    \
      af[mi] = *(const short8*)&As[B_][(row << 5) + (p << 3)];                 \
    }                                                                          \
    _Pragma("unroll")                                                          \
    for (int ni = 0; ni < 2; ni++) {                                           \
      int row = (wn << 5) + (ni << 4) + lr;                                    \
      bf2[ni] = *(const short8*)&Bs[B_][(row << 5) + (p << 3)];                \
    }                                                                          \
    _Pragma("unroll")                                                          \
    for (int mi = 0; mi < 8; mi++)                                             \
      _Pragma("unroll")                                                        \
      for (int ni = 0; ni < 2; ni++)                                           \
        acc[mi][ni] = __builtin_amdgcn_mfma_f32_16x16x32_bf16(                 \
            af[mi], bf2[ni], acc[mi][ni], 0, 0, 0);                            \
  } while (0)

  const int NK = DF / G2BK;  // 256
  int cur = 0;
  G2_STAGE(0, 0);
  __syncthreads();
  for (int kt = 0; kt < NK - 1; ++kt) {
    G2_STAGE(cur ^ 1, (kt + 1) * G2BK);
    G2_COMPUTE(cur);
    __syncthreads();
    cur ^= 1;
  }
  G2_COMPUTE(cur);

  const int l4 = (lane >> 4) << 2;
#pragma unroll
  for (int mi = 0; mi < 8; mi++) {
#pragma unroll
    for (int r = 0; r < 4; r++) {
      int lrow = (wm << 7) + (mi << 4) + l4 + r;
      if (lrow < nvalid) {
        int tok = sorted[row0 + lrow];
        float wv = topw[tok];
        size_t base = (size_t)tok * DM + n0 + (wn << 5) + lr;
#pragma unroll
        for (int ni = 0; ni < 2; ni++)
          out[base + (ni << 4)] = acc[mi][ni][r] * wv;
      }
    }
  }
#undef G2_STAGE
#undef G2_COMPUTE
}

// ================= fallback fp32-weight kernels =================
__global__ __launch_bounds__(512, 4) void gemm1_f32_kernel(
    const float* __restrict__ x, const float* __restrict__ Wg,
    const float* __restrict__ Wu, const int* __restrict__ tiles,
    const int* __restrict__ sorted, unsigned short* __restrict__ hbuf) {
  const int slot = blockIdx.x;
  const int e = tiles[slot * 3 + 0];
  const int row0 = tiles[slot * 3 + 1];
  const int nvalid = tiles[slot * 3 + 2];
  if (nvalid == 0) return;
  const int n0 = blockIdx.y * BN;

  __shared__ __align__(16) unsigned short As[BM][LDK];
  __shared__ __align__(16) unsigned short Bg[BN][LDK];
  __shared__ __align__(16) unsigned short Bu[BN][LDK];

  const int t = threadIdx.x;
  const int arow = t >> 1;
  const int ah = (t & 1) << 4;
  const int atok = (arow < nvalid) ? sorted[row0 + arow] : -1;
  const float* __restrict__ xrow = x + (size_t)(atok >= 0 ? atok : 0) * DM;
  const int bn = t & 63;
  const int bkq = (t >> 6) << 2;

  const size_t eo = (size_t)e * DM * DF;
  const float* __restrict__ Wge = Wg + eo;
  const float* __restrict__ Wue = Wu + eo;

  const int wv = t >> 6, lane = t & 63;
  const int wrow = (wv >> 1) << 6, wcol = (wv & 1) << 5;
  const int lr = lane & 15, lk = (lane >> 4) << 3;

  f32x4 accg[4][2], accu[4][2];
#pragma unroll
  for (int mi = 0; mi < 4; mi++)
#pragma unroll
    for (int ni = 0; ni < 2; ni++) {
      accg[mi][ni] = (f32x4){0.f, 0.f, 0.f, 0.f};
      accu[mi][ni] = (f32x4){0.f, 0.f, 0.f, 0.f};
    }

  for (int k0 = 0; k0 < DM; k0 += BKO) {
#pragma unroll
    for (int j = 0; j < 4; j++) {
      float4 v = make_float4(0.f, 0.f, 0.f, 0.f);
      if (atok >= 0) v = *(const float4*)(xrow + k0 + ah + (j << 2));
      ushort4 pv;
      pv.x = f2bf(v.x); pv.y = f2bf(v.y); pv.z = f2bf(v.z); pv.w = f2bf(v.w);
      *(ushort4*)&As[arow][ah + (j << 2)] = pv;
    }
    {
      const float* pg = Wge + (size_t)(k0 + bkq) * DF + n0 + bn;
      const float* pu = Wue + (size_t)(k0 + bkq) * DF + n0 + bn;
      ushort4 vg, vu;
      vg.x = f2bf(pg[0]);              vu.x = f2bf(pu[0]);
      vg.y = f2bf(pg[(size_t)DF]);     vu.y = f2bf(pu[(size_t)DF]);
      vg.z = f2bf(pg[(size_t)2 * DF]); vu.z = f2bf(pu[(size_t)2 * DF]);
      vg.w = f2bf(pg[(size_t)3 * DF]); vu.w = f2bf(pu[(size_t)3 * DF]);
      *(ushort4*)&Bg[bn][bkq] = vg;
      *(ushort4*)&Bu[bn][bkq] = vu;
    }
    __syncthreads();

    short8 af[4], bgf[2], buf2[2];
#pragma unroll
    for (int mi = 0; mi < 4; mi++)
      af[mi] = *(const short8*)&As[wrow + (mi << 4) + lr][lk];
#pragma unroll
    for (int ni = 0; ni < 2; ni++) {
      bgf[ni]  = *(const short8*)&Bg[wcol + (ni << 4) + lr][lk];
      buf2[ni] = *(const short8*)&Bu[wcol + (ni << 4) + lr][lk];
    }
#pragma unroll
    for (int mi = 0; mi < 4; mi++)
#pragma unroll
      for (int ni = 0; ni < 2; ni++) {
        accg[mi][ni] = __builtin_amdgcn_mfma_f32_16x16x32_bf16(af[mi], bgf[ni], accg[mi][ni], 0, 0, 0);
        accu[mi][ni] = __builtin_amdgcn_mfma_f32_16x16x32_bf16(af[mi], buf2[ni], accu[mi][ni], 0, 0, 0);
      }
    __syncthreads();
  }

  const int l4 = (lane >> 4) << 2;
#pragma unroll
  for (int mi = 0; mi < 4; mi++) {
#pragma unroll
    for (int r = 0; r < 4; r++) {
      int lrow = wrow + (mi << 4) + l4 + r;
      if (lrow < nvalid) {
        size_t base = (size_t)(row0 + lrow) * DF + n0 + wcol + lr;
#pragma unroll
        for (int ni = 0; ni < 2; ni++) {
          float g = accg[mi][ni][r];
          float u = accu[mi][ni][r];
          float hv = (g / (1.f + __expf(-g))) * u;
          hbuf[base + (ni << 4)] = f2bf(hv);
        }
      }
    }
  }
}

__global__ __launch_bounds__(512, 4) void gemm2_f32_kernel(
    const unsigned short* __restrict__ hbuf, const float* __restrict__ Wd,
    const int* __restrict__ tiles, const int* __restrict__ sorted,
    const float* __restrict__ topw, float* __restrict__ out) {
  const int slot = blockIdx.x;
  const int e = tiles[slot * 3 + 0];
  const int row0 = tiles[slot * 3 + 1];
  const int nvalid = tiles[slot * 3 + 2];
  if (nvalid == 0) return;
  const int n0 = blockIdx.y * BN;

  __shared__ __align__(16) unsigned short As[BM][LDK];
  __shared__ __align__(16) unsigned short Bs[BN][LDK];

  const int t = threadIdx.x;
  const int arow = t >> 1;
  const int ah = (t & 1) << 4;
  const int bn = t & 63;
  const int bkq = (t >> 6) << 2;
  const float* __restrict__ Wde = Wd + (size_t)e * DF * DM;

  const int wv = t >> 6, lane = t & 63;
  const int wrow = (wv >> 1) << 6, wcol = (wv & 1) << 5;
  const int lr = lane & 15, lk = (lane >> 4) << 3;

  f32x4 acc[4][2];
#pragma unroll
  for (int mi = 0; mi < 4; mi++)
#pragma unroll
    for (int ni = 0; ni < 2; ni++) acc[mi][ni] = (f32x4){0.f, 0.f, 0.f, 0.f};

  const unsigned short* __restrict__ hrow =
      hbuf + (size_t)(row0 + (arow < nvalid ? arow : 0)) * DF;

  for (int k0 = 0; k0 < DF; k0 += BKO) {
    {
      short8 v0 = (short8){0,0,0,0,0,0,0,0}, v1 = v0;
      if (arow < nvalid) {
        v0 = *(const short8*)(hrow + k0 + ah);
        v1 = *(const short8*)(hrow + k0 + ah + 8);
      }
      *(short8*)&As[arow][ah] = v0;
      *(short8*)&As[arow][ah + 8] = v1;
    }
    {
      const float* pd = Wde + (size_t)(k0 + bkq) * DM + n0 + bn;
      ushort4 vd;
      vd.x = f2bf(pd[0]);
      vd.y = f2bf(pd[(size_t)DM]);
      vd.z = f2bf(pd[(size_t)2 * DM]);
      vd.w = f2bf(pd[(size_t)3 * DM]);
      *(ushort4*)&Bs[bn][bkq] = vd;
    }
    __syncthreads();

    short8 af[4], bf2[2];
#pragma unroll
    for (int mi = 0; mi < 4; mi++)
      af[mi] = *(const short8*)&As[wrow + (mi << 4) + lr][lk];
#pragma unroll
    for (int ni = 0; ni < 2; ni++)
      bf2[ni] = *(const short8*)&Bs[wcol + (ni << 4) + lr][lk];
#pragma unroll
    for (int mi = 0; mi < 4; mi++)
#pragma unroll
      for (int ni = 0; ni < 2; ni++)
        acc[mi][ni] = __builtin_amdgcn_mfma_f32_16x16x32_bf16(af[mi], bf2[ni], acc[mi][ni], 0, 0, 0);
    __syncthreads();
  }

  const int l4 = (lane >> 4) << 2;
#pragma unroll
  for (int mi = 0; mi < 4; mi++) {
#pragma unroll
    for (int r = 0; r < 4; r++) {
      int lrow = wrow + (mi << 4) + l4 + r;
      if (lrow < nvalid) {
        int tok = sorted[row0 + lrow];
        float w = topw[tok];
        size_t base = (size_t)tok * DM + n0 + wcol + lr;
#pragma unroll
        for (int ni = 0; ni < 2; ni++)
          out[base + (ni << 4)] = acc[mi][ni][r] * w;
      }
    }
  }
}

extern "C" void kernel_launch(void* const* d_in, const int* in_sizes, int n_in,
                              void* d_out, int out_size, void* d_ws, size_t ws_size,
                              hipStream_t stream) {
  const float* x  = (const float*)d_in[0];
  const float* Wr = (const float*)d_in[1];
  const float* br = (const float*)d_in[2];
  const float* Wg = (const float*)d_in[3];
  const float* Wu = (const float*)d_in[4];
  const float* Wd = (const float*)d_in[5];
  float* out = (float*)d_out;

  const size_t XS_ELEMS = (size_t)(T_TOK + PADROWS) * DM;
  const size_t HB_ELEMS = (size_t)(T_TOK + PADROWS) * DF;
  const size_t W_ELEMS  = (size_t)NE * DM * DF;
  const size_t NEED = (XS_ELEMS + HB_ELEMS + 3 * W_ELEMS) * 2 + (1 << 20);

  if (ws_size >= NEED) {
    // ---------- bf16 fast path ----------
    unsigned short* xs = (unsigned short*)d_ws;
    unsigned short* hb = xs + XS_ELEMS;
    unsigned short* wg = hb + HB_ELEMS;
    unsigned short* wu = wg + W_ELEMS;
    unsigned short* wd = wu + W_ELEMS;
    int* meta = (int*)(wd + W_ELEMS);
    int* top_idx = meta;
    int* sorted  = meta + 4096;
    int* counts  = meta + 8192;
    int* offs    = meta + 8196;
    int* cursors = meta + 8201;
    int* tiles   = meta + 8208;
    float* topw  = (float*)(meta + 8320);

    hipMemsetAsync(counts, 0, NE * sizeof(int), stream);
    router_kernel<<<dim3((T_TOK * 64) / 256), 256, 0, stream>>>(x, Wr, br, top_idx, topw, counts);
    scan_kernel<<<1, 1, 0, stream>>>(counts, offs, cursors, tiles);
    scatter_kernel<<<dim3(T_TOK / 256), 256, 0, stream>>>(top_idx, cursors, sorted);
    gather_x_kernel<<<dim3(T_TOK + PADROWS), 256, 0, stream>>>(x, sorted, xs);
    // Wg/Wu: [E][DM][DF] -> [E][DF][DM]; Wd: [E][DF][DM] -> [E][DM][DF]
    transpose_cvt_kernel<<<dim3(DF / 64, DM / 64, NE), 256, 0, stream>>>(Wg, wg, DM, DF);
    transpose_cvt_kernel<<<dim3(DF / 64, DM / 64, NE), 256, 0, stream>>>(Wu, wu, DM, DF);
    transpose_cvt_kernel<<<dim3(DM / 64, DF / 64, NE), 256, 0, stream>>>(Wd, wd, DF, DM);
    gemm1_bf16_kernel<<<dim3(MAX_TILES, DF / GBN), 512, 0, stream>>>(xs, wg, wu, tiles, hb);
    gemm2_bf16_kernel<<<dim3(MAX_TILES, DM / GBN), 512, 0, stream>>>(hb, wd, tiles, sorted, topw, out);
  } else {
    // ---------- fallback path ----------
    const size_t H_BYTES = (size_t)T_TOK * DF * 2;
    unsigned short* hbuf = (unsigned short*)d_ws;
    int* meta = (int*)((char*)d_ws + H_BYTES);
    int* top_idx = meta;
    int* sorted  = meta + 4096;
    int* counts  = meta + 8192;
    int* offs    = meta + 8196;
    int* cursors = meta + 8201;
    int* tiles   = meta + 8208;
    float* topw  = (float*)(meta + 8320);

    hipMemsetAsync(counts, 0, NE * sizeof(int), stream);
    router_kernel<<<dim3((T_TOK * 64) / 256), 256, 0, stream>>>(x, Wr, br, top_idx, topw, counts);
    scan_kernel<<<1, 1, 0, stream>>>(counts, offs, cursors, tiles);
    scatter_kernel<<<dim3(T_TOK / 256), 256, 0, stream>>>(top_idx, cursors, sorted);
    gemm1_f32_kernel<<<dim3(MAX_TILES, DF / BN), 512, 0, stream>>>(x, Wg, Wu, tiles, sorted, hbuf);
    gemm2_f32_kernel<<<dim3(MAX_TILES, DM / BN), 512, 0, stream>>>(hbuf, Wd, tiles, sorted, topw, out);
  }
}

// Round 11
// 869.144 us; speedup vs baseline: 1.1218x; 1.0331x over previous
//
#include <hip/hip_runtime.h>

#define T_TOK 4096
#define DM 2048
#define DF 8192
#define NE 4
#define BM 256
#define BN 64        // fallback geometry
#define GBN 128      // N tile
#define GBK 64       // gemm1 K step
#define G2BK 32      // gemm2 K step
#define BKO 32
#define MAX_TILES 20
#define PADROWS 256
#define LDK (BKO + 8)

typedef __attribute__((ext_vector_type(8))) short short8;
typedef __attribute__((ext_vector_type(4))) float f32x4;

__device__ __forceinline__ unsigned short f2bf(float f) {
  unsigned int u = __float_as_uint(f);
  u += 0x7fffu + ((u >> 16) & 1u);   // round-to-nearest-even
  return (unsigned short)(u >> 16);
}

// async global->LDS, 16B/lane; LDS base wave-uniform (HW: base + lane*16)
__device__ __forceinline__ void gld_lds16(const unsigned short* g, unsigned short* l) {
  __builtin_amdgcn_global_load_lds(
      (const __attribute__((address_space(1))) unsigned int*)g,
      (__attribute__((address_space(3))) unsigned int*)l, 16, 0, 0);
}

// ---------------- router ----------------
__global__ __launch_bounds__(256) void router_kernel(
    const float* __restrict__ x, const float* __restrict__ Wr,
    const float* __restrict__ br, int* __restrict__ top_idx,
    float* __restrict__ top_w, int* __restrict__ counts) {
  int tok = (blockIdx.x * blockDim.x + threadIdx.x) >> 6;
  int lane = threadIdx.x & 63;
  if (tok >= T_TOK) return;
  const float* xr = x + (size_t)tok * DM;
  float s0 = 0.f, s1 = 0.f, s2 = 0.f, s3 = 0.f;
  for (int j = lane; j < DM; j += 64) {
    float xv = xr[j];
    float4 w = *(const float4*)(Wr + (size_t)j * NE);
    s0 += xv * w.x; s1 += xv * w.y; s2 += xv * w.z; s3 += xv * w.w;
  }
#pragma unroll
  for (int off = 32; off > 0; off >>= 1) {
    s0 += __shfl_xor(s0, off);
    s1 += __shfl_xor(s1, off);
    s2 += __shfl_xor(s2, off);
    s3 += __shfl_xor(s3, off);
  }
  if (lane == 0) {
    float l[NE] = {s0 + br[0], s1 + br[1], s2 + br[2], s3 + br[3]};
    int bi = 0; float bm = l[0];
#pragma unroll
    for (int e = 1; e < NE; e++) if (l[e] > bm) { bm = l[e]; bi = e; }
    float s = 0.f;
#pragma unroll
    for (int e = 0; e < NE; e++) s += __expf(l[e] - bm);
    top_idx[tok] = bi;
    top_w[tok] = 1.0f / s;
    atomicAdd(&counts[bi], 1);
  }
}

// ---------------- scan ----------------
__global__ void scan_kernel(const int* __restrict__ counts, int* __restrict__ offs,
                            int* __restrict__ cursors, int* __restrict__ tiles) {
  if (threadIdx.x != 0 || blockIdx.x != 0) return;
  int offv[NE + 1];
  offv[0] = 0;
  for (int e = 0; e < NE; e++) offv[e + 1] = offv[e] + counts[e];
  for (int e = 0; e <= NE; e++) offs[e] = offv[e];
  for (int e = 0; e < NE; e++) cursors[e] = offv[e];
  int nt = 0;
  for (int e = 0; e < NE; e++) {
    int c = counts[e];
    for (int s = 0; s < c; s += BM) {
      tiles[nt * 3 + 0] = e;
      tiles[nt * 3 + 1] = offv[e] + s;
      tiles[nt * 3 + 2] = (c - s < BM) ? (c - s) : BM;
      nt++;
    }
  }
  for (; nt < MAX_TILES; nt++) {
    tiles[nt * 3 + 0] = 0; tiles[nt * 3 + 1] = 0; tiles[nt * 3 + 2] = 0;
  }
}

// ---------------- scatter ----------------
__global__ __launch_bounds__(256) void scatter_kernel(
    const int* __restrict__ top_idx, int* __restrict__ cursors,
    int* __restrict__ sorted) {
  int t = blockIdx.x * blockDim.x + threadIdx.x;
  if (t >= T_TOK) return;
  int e = top_idx[t];
  int p = atomicAdd(&cursors[e], 1);
  sorted[p] = t;
}

// ---------------- gather_x ----------------
__global__ __launch_bounds__(256) void gather_x_kernel(
    const float* __restrict__ x, const int* __restrict__ sorted,
    unsigned short* __restrict__ xs) {
  const int row = blockIdx.x;
  const int t = threadIdx.x;
  unsigned short* orow = xs + (size_t)row * DM + (t << 3);
  if (row >= T_TOK) {
    short8 z = (short8){0,0,0,0,0,0,0,0};
    *(short8*)orow = z;
    return;
  }
  const float* irow = x + (size_t)sorted[row] * DM + (t << 3);
  float4 a = *(const float4*)irow;
  float4 b = *(const float4*)(irow + 4);
  short8 p;
  p[0] = (short)f2bf(a.x); p[1] = (short)f2bf(a.y);
  p[2] = (short)f2bf(a.z); p[3] = (short)f2bf(a.w);
  p[4] = (short)f2bf(b.x); p[5] = (short)f2bf(b.y);
  p[6] = (short)f2bf(b.z); p[7] = (short)f2bf(b.w);
  *(short8*)orow = p;
}

// ---------------- transpose+convert: fp32 [R][C] -> bf16 [C][R] ----------------
__global__ __launch_bounds__(256) void transpose_cvt_kernel(
    const float* __restrict__ in, unsigned short* __restrict__ out, int R, int C) {
  __shared__ float tile[64][65];
  const size_t eo = (size_t)blockIdx.z * (size_t)R * (size_t)C;
  const float* inp = in + eo;
  unsigned short* outp = out + eo;
  const int r0 = blockIdx.y << 6, c0 = blockIdx.x << 6;
  const int t = threadIdx.x;
  const int lrow = t >> 4, lcol = (t & 15) << 2;
#pragma unroll
  for (int i = 0; i < 4; i++) {
    float4 v = *(const float4*)(inp + (size_t)(r0 + (i << 4) + lrow) * C + c0 + lcol);
    *(float4*)&tile[(i << 4) + lrow][lcol] = v;
  }
  __syncthreads();
  const int gg = t & 7, cc = t >> 3;
#pragma unroll
  for (int cp = 0; cp < 2; cp++) {
    int c = cc + (cp << 5);
    short8 pv;
#pragma unroll
    for (int i = 0; i < 8; i++) pv[i] = (short)f2bf(tile[(gg << 3) + i][c]);
    *(short8*)(outp + (size_t)(c0 + c) * R + r0 + (gg << 3)) = pv;
  }
}

// ---------------- gemm1 (bf16, 2-phase dbuf) — proven R5 form ----------------
// 256x128x64 tile, 8 waves (2M x 4N), wave tile 128x32 (g+u), LDS 128 KB, 1 blk/CU.
__global__ __launch_bounds__(512, 2) void gemm1_bf16_kernel(
    const unsigned short* __restrict__ xs, const unsigned short* __restrict__ wg,
    const unsigned short* __restrict__ wu, const int* __restrict__ tiles,
    unsigned short* __restrict__ hbuf) {
  const int slot = blockIdx.x;
  const int e = tiles[slot * 3 + 0];
  const int row0 = tiles[slot * 3 + 1];
  const int nvalid = tiles[slot * 3 + 2];
  if (nvalid == 0) return;
  const int n0 = blockIdx.y * GBN;

  __shared__ __align__(16) unsigned short As[2][BM * GBK];   // 64 KB
  __shared__ __align__(16) unsigned short Bg[2][GBN * GBK];  // 32 KB
  __shared__ __align__(16) unsigned short Bu[2][GBN * GBK];  // 32 KB

  const int t = threadIdx.x;
  const int w = t >> 6, lane = t & 63;
  const int l3 = lane >> 3;
  const int swz = (lane & 7) ^ l3;          // inverse-swizzled source granule
  const int lr = lane & 15;
  const int wm = w >> 2, wn = w & 3;

  const unsigned short* wge = wg + (size_t)e * DM * DF;
  const unsigned short* wue = wu + (size_t)e * DM * DF;

  const unsigned short* sA = xs + (size_t)(row0 + (w << 6) + l3) * DM + (swz << 3);
  const unsigned short* sBg = wge + (size_t)(n0 + ((w - 4) << 6) + l3) * DM + (swz << 3);
  const unsigned short* sBu = wue + (size_t)(n0 + ((w - 6) << 6) + l3) * DM + (swz << 3);

  f32x4 accg[8][2], accu[8][2];
#pragma unroll
  for (int mi = 0; mi < 8; mi++)
#pragma unroll
    for (int ni = 0; ni < 2; ni++) {
      accg[mi][ni] = (f32x4){0.f, 0.f, 0.f, 0.f};
      accu[mi][ni] = (f32x4){0.f, 0.f, 0.f, 0.f};
    }

#define G1_STAGE(B, K0)                                                        \
  do {                                                                         \
    if (w < 4) {                                                               \
      unsigned short* d = &As[B][(w << 6) << 6];                               \
      _Pragma("unroll")                                                        \
      for (int j = 0; j < 8; j++)                                              \
        gld_lds16(sA + (size_t)(j << 3) * DM + (K0), d + (j << 9));            \
    } else if (w < 6) {                                                        \
      unsigned short* d = &Bg[B][((w - 4) << 6) << 6];                         \
      _Pragma("unroll")                                                        \
      for (int j = 0; j < 8; j++)                                              \
        gld_lds16(sBg + (size_t)(j << 3) * DM + (K0), d + (j << 9));           \
    } else {                                                                   \
      unsigned short* d = &Bu[B][((w - 6) << 6) << 6];                         \
      _Pragma("unroll")                                                        \
      for (int j = 0; j < 8; j++)                                              \
        gld_lds16(sBu + (size_t)(j << 3) * DM + (K0), d + (j << 9));           \
    }                                                                          \
  } while (0)

#define G1_COMPUTE(B)                                                          \
  do {                                                                         \
    _Pragma("unroll")                                                          \
    for (int h = 0; h < 2; h++) {                                              \
      const int gq = (h << 2) + (lane >> 4);                                   \
      const int g = gq ^ (lr & 7);                                             \
      short8 af[8], bgf[2], buf2[2];                                           \
      _Pragma("unroll")                                                        \
      for (int mi = 0; mi < 8; mi++) {                                         \
        int row = (wm << 7) + (mi << 4) + lr;                                  \
        af[mi] = *(const short8*)&As[B][(row << 6) + (g << 3)];                \
      }                                                                        \
      _Pragma("unroll")                                                        \
      for (int ni = 0; ni < 2; ni++) {                                         \
        int row = (wn << 5) + (ni << 4) + lr;                                  \
        bgf[ni]  = *(const short8*)&Bg[B][(row << 6) + (g << 3)];              \
        buf2[ni] = *(const short8*)&Bu[B][(row << 6) + (g << 3)];              \
      }                                                                        \
      _Pragma("unroll")                                                        \
      for (int mi = 0; mi < 8; mi++)                                           \
        _Pragma("unroll")                                                      \
        for (int ni = 0; ni < 2; ni++) {                                       \
          accg[mi][ni] = __builtin_amdgcn_mfma_f32_16x16x32_bf16(              \
              af[mi], bgf[ni], accg[mi][ni], 0, 0, 0);                         \
          accu[mi][ni] = __builtin_amdgcn_mfma_f32_16x16x32_bf16(              \
              af[mi], buf2[ni], accu[mi][ni], 0, 0, 0);                        \
        }                                                                      \
    }                                                                          \
  } while (0)

  const int NK = DM / GBK;  // 32
  int cur = 0;
  G1_STAGE(0, 0);
  __syncthreads();
  for (int kt = 0; kt < NK - 1; ++kt) {
    G1_STAGE(cur ^ 1, (kt + 1) * GBK);
    G1_COMPUTE(cur);
    __syncthreads();
    cur ^= 1;
  }
  G1_COMPUTE(cur);

  const int l4 = (lane >> 4) << 2;
#pragma unroll
  for (int mi = 0; mi < 8; mi++) {
#pragma unroll
    for (int r = 0; r < 4; r++) {
      int lrow = (wm << 7) + (mi << 4) + l4 + r;
      if (lrow < nvalid) {
        size_t base = (size_t)(row0 + lrow) * DF + n0 + (wn << 5) + lr;
#pragma unroll
        for (int ni = 0; ni < 2; ni++) {
          float gv = accg[mi][ni][r];
          float uv = accu[mi][ni][r];
          float hv = (gv / (1.f + __expf(-gv))) * uv;
          hbuf[base + (ni << 4)] = f2bf(hv);
        }
      }
    }
  }
#undef G1_STAGE
#undef G1_COMPUTE
}

// ---------------- gemm2 v2 (bf16, 2-phase dbuf, 128-row half-tiles, 4 blk/CU) --------
// Block: 128 rows (half of a 256-tile) x 128 cols, 256 threads (4 waves, 2M x 2N),
// wave tile 64x64 (acc 4x4), G2BK=32, LDS 32 KB -> 4 blocks/CU, 640 blocks all resident.
__global__ __launch_bounds__(256, 4) void gemm2_bf16_kernel(
    const unsigned short* __restrict__ hbuf, const unsigned short* __restrict__ wd,
    const int* __restrict__ tiles, const int* __restrict__ sorted,
    const float* __restrict__ topw, float* __restrict__ out) {
  const int slot = blockIdx.x;
  const int e = tiles[slot * 3 + 0];
  const int row0t = tiles[slot * 3 + 1];
  const int nvalid_t = tiles[slot * 3 + 2];
  const int half = blockIdx.z;
  const int nvh = nvalid_t - (half << 7);
  if (nvh <= 0) return;
  const int nvalid = (nvh < 128) ? nvh : 128;
  const int row0 = row0t + (half << 7);
  const int n0 = blockIdx.y * GBN;

  __shared__ __align__(16) unsigned short As[2][128 * G2BK];  // 2 x 8 KB
  __shared__ __align__(16) unsigned short Bs[2][GBN * G2BK];  // 2 x 8 KB

  const int t = threadIdx.x;
  const int w = t >> 6, lane = t & 63;   // 4 waves
  const int lr = lane & 15;
  const int wm = w >> 1, wn = w & 1;

  // staging map (32-wide rows, 4 granules/row): lane -> row lane>>2 within 16-row chunk,
  // phys granule lane&3 holds source granule (lane&3)^((lane>>3)&3); read swizzle p=q^((lr>>1)&3)
  const int srow = lane >> 2;
  const int sg = (lane & 3) ^ ((lane >> 3) & 3);

  const unsigned short* wde = wd + (size_t)e * DM * DF;
  // waves 0-1 stage A (4 chunks each: rows w*64 + j*16), waves 2-3 stage B likewise
  const unsigned short* sA = hbuf + (size_t)(row0 + (w << 6) + srow) * DF + (sg << 3);
  const unsigned short* sB = wde + (size_t)(n0 + ((w - 2) << 6) + srow) * DF + (sg << 3);

  f32x4 acc[4][4];
#pragma unroll
  for (int mi = 0; mi < 4; mi++)
#pragma unroll
    for (int ni = 0; ni < 4; ni++) acc[mi][ni] = (f32x4){0.f, 0.f, 0.f, 0.f};

#define G2_STAGE(B_, K0)                                                       \
  do {                                                                         \
    if (w < 2) {                                                               \
      _Pragma("unroll")                                                        \
      for (int j = 0; j < 4; j++)                                              \
        gld_lds16(sA + (size_t)(j << 4) * DF + (K0),                           \
                  &As[B_][((w << 2) + j) << 9]);                               \
    } else {                                                                   \
      _Pragma("unroll")                                                        \
      for (int j = 0; j < 4; j++)                                              \
        gld_lds16(sB + (size_t)(j << 4) * DF + (K0),                           \
                  &Bs[B_][(((w - 2) << 2) + j) << 9]);                         \
    }                                                                          \
  } while (0)

#define G2_COMPUTE(B_)                                                         \
  do {                                                                         \
    const int q = lane >> 4;                                                   \
    const int p = q ^ ((lr >> 1) & 3);                                         \
    short8 af[4], bf2[4];                                                      \
    _Pragma("unroll")                                                          \
    for (int mi = 0; mi < 4; mi++) {                                           \
      int row = (wm << 6) + (mi << 4) + lr;                                    \
      af[mi] = *(const short8*)&As[B_][(row << 5) + (p << 3)];                 \
    }                                                                          \
    _Pragma("unroll")                                                          \
    for (int ni = 0; ni < 4; ni++) {                                           \
      int row = (wn << 6) + (ni << 4) + lr;                                    \
      bf2[ni] = *(const short8*)&Bs[B_][(row << 5) + (p << 3)];                \
    }                                                                          \
    _Pragma("unroll")                                                          \
    for (int mi = 0; mi < 4; mi++)                                             \
      _Pragma("unroll")                                                        \
      for (int ni = 0; ni < 4; ni++)                                           \
        acc[mi][ni] = __builtin_amdgcn_mfma_f32_16x16x32_bf16(                 \
            af[mi], bf2[ni], acc[mi][ni], 0, 0, 0);                            \
  } while (0)

  const int NK = DF / G2BK;  // 256
  int cur = 0;
  G2_STAGE(0, 0);
  __syncthreads();
  for (int kt = 0; kt < NK - 1; ++kt) {
    G2_STAGE(cur ^ 1, (kt + 1) * G2BK);
    G2_COMPUTE(cur);
    __syncthreads();
    cur ^= 1;
  }
  G2_COMPUTE(cur);

  const int l4 = (lane >> 4) << 2;
#pragma unroll
  for (int mi = 0; mi < 4; mi++) {
#pragma unroll
    for (int r = 0; r < 4; r++) {
      int lrow = (wm << 6) + (mi << 4) + l4 + r;
      if (lrow < nvalid) {
        int tok = sorted[row0 + lrow];
        float wv = topw[tok];
        size_t base = (size_t)tok * DM + n0 + (wn << 6) + lr;
#pragma unroll
        for (int ni = 0; ni < 4; ni++)
          out[base + (ni << 4)] = acc[mi][ni][r] * wv;
      }
    }
  }
#undef G2_STAGE
#undef G2_COMPUTE
}

// ================= fallback fp32-weight kernels =================
__global__ __launch_bounds__(512, 4) void gemm1_f32_kernel(
    const float* __restrict__ x, const float* __restrict__ Wg,
    const float* __restrict__ Wu, const int* __restrict__ tiles,
    const int* __restrict__ sorted, unsigned short* __restrict__ hbuf) {
  const int slot = blockIdx.x;
  const int e = tiles[slot * 3 + 0];
  const int row0 = tiles[slot * 3 + 1];
  const int nvalid = tiles[slot * 3 + 2];
  if (nvalid == 0) return;
  const int n0 = blockIdx.y * BN;

  __shared__ __align__(16) unsigned short As[BM][LDK];
  __shared__ __align__(16) unsigned short Bg[BN][LDK];
  __shared__ __align__(16) unsigned short Bu[BN][LDK];

  const int t = threadIdx.x;
  const int arow = t >> 1;
  const int ah = (t & 1) << 4;
  const int atok = (arow < nvalid) ? sorted[row0 + arow] : -1;
  const float* __restrict__ xrow = x + (size_t)(atok >= 0 ? atok : 0) * DM;
  const int bn = t & 63;
  const int bkq = (t >> 6) << 2;

  const size_t eo = (size_t)e * DM * DF;
  const float* __restrict__ Wge = Wg + eo;
  const float* __restrict__ Wue = Wu + eo;

  const int wv = t >> 6, lane = t & 63;
  const int wrow = (wv >> 1) << 6, wcol = (wv & 1) << 5;
  const int lr = lane & 15, lk = (lane >> 4) << 3;

  f32x4 accg[4][2], accu[4][2];
#pragma unroll
  for (int mi = 0; mi < 4; mi++)
#pragma unroll
    for (int ni = 0; ni < 2; ni++) {
      accg[mi][ni] = (f32x4){0.f, 0.f, 0.f, 0.f};
      accu[mi][ni] = (f32x4){0.f, 0.f, 0.f, 0.f};
    }

  for (int k0 = 0; k0 < DM; k0 += BKO) {
#pragma unroll
    for (int j = 0; j < 4; j++) {
      float4 v = make_float4(0.f, 0.f, 0.f, 0.f);
      if (atok >= 0) v = *(const float4*)(xrow + k0 + ah + (j << 2));
      ushort4 pv;
      pv.x = f2bf(v.x); pv.y = f2bf(v.y); pv.z = f2bf(v.z); pv.w = f2bf(v.w);
      *(ushort4*)&As[arow][ah + (j << 2)] = pv;
    }
    {
      const float* pg = Wge + (size_t)(k0 + bkq) * DF + n0 + bn;
      const float* pu = Wue + (size_t)(k0 + bkq) * DF + n0 + bn;
      ushort4 vg, vu;
      vg.x = f2bf(pg[0]);              vu.x = f2bf(pu[0]);
      vg.y = f2bf(pg[(size_t)DF]);     vu.y = f2bf(pu[(size_t)DF]);
      vg.z = f2bf(pg[(size_t)2 * DF]); vu.z = f2bf(pu[(size_t)2 * DF]);
      vg.w = f2bf(pg[(size_t)3 * DF]); vu.w = f2bf(pu[(size_t)3 * DF]);
      *(ushort4*)&Bg[bn][bkq] = vg;
      *(ushort4*)&Bu[bn][bkq] = vu;
    }
    __syncthreads();

    short8 af[4], bgf[2], buf2[2];
#pragma unroll
    for (int mi = 0; mi < 4; mi++)
      af[mi] = *(const short8*)&As[wrow + (mi << 4) + lr][lk];
#pragma unroll
    for (int ni = 0; ni < 2; ni++) {
      bgf[ni]  = *(const short8*)&Bg[wcol + (ni << 4) + lr][lk];
      buf2[ni] = *(const short8*)&Bu[wcol + (ni << 4) + lr][lk];
    }
#pragma unroll
    for (int mi = 0; mi < 4; mi++)
#pragma unroll
      for (int ni = 0; ni < 2; ni++) {
        accg[mi][ni] = __builtin_amdgcn_mfma_f32_16x16x32_bf16(af[mi], bgf[ni], accg[mi][ni], 0, 0, 0);
        accu[mi][ni] = __builtin_amdgcn_mfma_f32_16x16x32_bf16(af[mi], buf2[ni], accu[mi][ni], 0, 0, 0);
      }
    __syncthreads();
  }

  const int l4 = (lane >> 4) << 2;
#pragma unroll
  for (int mi = 0; mi < 4; mi++) {
#pragma unroll
    for (int r = 0; r < 4; r++) {
      int lrow = wrow + (mi << 4) + l4 + r;
      if (lrow < nvalid) {
        size_t base = (size_t)(row0 + lrow) * DF + n0 + wcol + lr;
#pragma unroll
        for (int ni = 0; ni < 2; ni++) {
          float g = accg[mi][ni][r];
          float u = accu[mi][ni][r];
          float hv = (g / (1.f + __expf(-g))) * u;
          hbuf[base + (ni << 4)] = f2bf(hv);
        }
      }
    }
  }
}

__global__ __launch_bounds__(512, 4) void gemm2_f32_kernel(
    const unsigned short* __restrict__ hbuf, const float* __restrict__ Wd,
    const int* __restrict__ tiles, const int* __restrict__ sorted,
    const float* __restrict__ topw, float* __restrict__ out) {
  const int slot = blockIdx.x;
  const int e = tiles[slot * 3 + 0];
  const int row0 = tiles[slot * 3 + 1];
  const int nvalid = tiles[slot * 3 + 2];
  if (nvalid == 0) return;
  const int n0 = blockIdx.y * BN;

  __shared__ __align__(16) unsigned short As[BM][LDK];
  __shared__ __align__(16) unsigned short Bs[BN][LDK];

  const int t = threadIdx.x;
  const int arow = t >> 1;
  const int ah = (t & 1) << 4;
  const int bn = t & 63;
  const int bkq = (t >> 6) << 2;
  const float* __restrict__ Wde = Wd + (size_t)e * DF * DM;

  const int wv = t >> 6, lane = t & 63;
  const int wrow = (wv >> 1) << 6, wcol = (wv & 1) << 5;
  const int lr = lane & 15, lk = (lane >> 4) << 3;

  f32x4 acc[4][2];
#pragma unroll
  for (int mi = 0; mi < 4; mi++)
#pragma unroll
    for (int ni = 0; ni < 2; ni++) acc[mi][ni] = (f32x4){0.f, 0.f, 0.f, 0.f};

  const unsigned short* __restrict__ hrow =
      hbuf + (size_t)(row0 + (arow < nvalid ? arow : 0)) * DF;

  for (int k0 = 0; k0 < DF; k0 += BKO) {
    {
      short8 v0 = (short8){0,0,0,0,0,0,0,0}, v1 = v0;
      if (arow < nvalid) {
        v0 = *(const short8*)(hrow + k0 + ah);
        v1 = *(const short8*)(hrow + k0 + ah + 8);
      }
      *(short8*)&As[arow][ah] = v0;
      *(short8*)&As[arow][ah + 8] = v1;
    }
    {
      const float* pd = Wde + (size_t)(k0 + bkq) * DM + n0 + bn;
      ushort4 vd;
      vd.x = f2bf(pd[0]);
      vd.y = f2bf(pd[(size_t)DM]);
      vd.z = f2bf(pd[(size_t)2 * DM]);
      vd.w = f2bf(pd[(size_t)3 * DM]);
      *(ushort4*)&Bs[bn][bkq] = vd;
    }
    __syncthreads();

    short8 af[4], bf2[2];
#pragma unroll
    for (int mi = 0; mi < 4; mi++)
      af[mi] = *(const short8*)&As[wrow + (mi << 4) + lr][lk];
#pragma unroll
    for (int ni = 0; ni < 2; ni++)
      bf2[ni] = *(const short8*)&Bs[wcol + (ni << 4) + lr][lk];
#pragma unroll
    for (int mi = 0; mi < 4; mi++)
#pragma unroll
      for (int ni = 0; ni < 2; ni++)
        acc[mi][ni] = __builtin_amdgcn_mfma_f32_16x16x32_bf16(af[mi], bf2[ni], acc[mi][ni], 0, 0, 0);
    __syncthreads();
  }

  const int l4 = (lane >> 4) << 2;
#pragma unroll
  for (int mi = 0; mi < 4; mi++) {
#pragma unroll
    for (int r = 0; r < 4; r++) {
      int lrow = wrow + (mi << 4) + l4 + r;
      if (lrow < nvalid) {
        int tok = sorted[row0 + lrow];
        float w = topw[tok];
        size_t base = (size_t)tok * DM + n0 + wcol + lr;
#pragma unroll
        for (int ni = 0; ni < 2; ni++)
          out[base + (ni << 4)] = acc[mi][ni][r] * w;
      }
    }
  }
}

extern "C" void kernel_launch(void* const* d_in, const int* in_sizes, int n_in,
                              void* d_out, int out_size, void* d_ws, size_t ws_size,
                              hipStream_t stream) {
  const float* x  = (const float*)d_in[0];
  const float* Wr = (const float*)d_in[1];
  const float* br = (const float*)d_in[2];
  const float* Wg = (const float*)d_in[3];
  const float* Wu = (const float*)d_in[4];
  const float* Wd = (const float*)d_in[5];
  float* out = (float*)d_out;

  const size_t XS_ELEMS = (size_t)(T_TOK + PADROWS) * DM;
  const size_t HB_ELEMS = (size_t)(T_TOK + PADROWS) * DF;
  const size_t W_ELEMS  = (size_t)NE * DM * DF;
  const size_t NEED = (XS_ELEMS + HB_ELEMS + 3 * W_ELEMS) * 2 + (1 << 20);

  if (ws_size >= NEED) {
    // ---------- bf16 fast path ----------
    unsigned short* xs = (unsigned short*)d_ws;
    unsigned short* hb = xs + XS_ELEMS;
    unsigned short* wg = hb + HB_ELEMS;
    unsigned short* wu = wg + W_ELEMS;
    unsigned short* wd = wu + W_ELEMS;
    int* meta = (int*)(wd + W_ELEMS);
    int* top_idx = meta;
    int* sorted  = meta + 4096;
    int* counts  = meta + 8192;
    int* offs    = meta + 8196;
    int* cursors = meta + 8201;
    int* tiles   = meta + 8208;
    float* topw  = (float*)(meta + 8320);

    hipMemsetAsync(counts, 0, NE * sizeof(int), stream);
    router_kernel<<<dim3((T_TOK * 64) / 256), 256, 0, stream>>>(x, Wr, br, top_idx, topw, counts);
    scan_kernel<<<1, 1, 0, stream>>>(counts, offs, cursors, tiles);
    scatter_kernel<<<dim3(T_TOK / 256), 256, 0, stream>>>(top_idx, cursors, sorted);
    gather_x_kernel<<<dim3(T_TOK + PADROWS), 256, 0, stream>>>(x, sorted, xs);
    // Wg/Wu: [E][DM][DF] -> [E][DF][DM]; Wd: [E][DF][DM] -> [E][DM][DF]
    transpose_cvt_kernel<<<dim3(DF / 64, DM / 64, NE), 256, 0, stream>>>(Wg, wg, DM, DF);
    transpose_cvt_kernel<<<dim3(DF / 64, DM / 64, NE), 256, 0, stream>>>(Wu, wu, DM, DF);
    transpose_cvt_kernel<<<dim3(DM / 64, DF / 64, NE), 256, 0, stream>>>(Wd, wd, DF, DM);
    gemm1_bf16_kernel<<<dim3(MAX_TILES, DF / GBN), 512, 0, stream>>>(xs, wg, wu, tiles, hb);
    gemm2_bf16_kernel<<<dim3(MAX_TILES, DM / GBN, 2), 256, 0, stream>>>(hb, wd, tiles, sorted, topw, out);
  } else {
    // ---------- fallback path ----------
    const size_t H_BYTES = (size_t)T_TOK * DF * 2;
    unsigned short* hbuf = (unsigned short*)d_ws;
    int* meta = (int*)((char*)d_ws + H_BYTES);
    int* top_idx = meta;
    int* sorted  = meta + 4096;
    int* counts  = meta + 8192;
    int* offs    = meta + 8196;
    int* cursors = meta + 8201;
    int* tiles   = meta + 8208;
    float* topw  = (float*)(meta + 8320);

    hipMemsetAsync(counts, 0, NE * sizeof(int), stream);
    router_kernel<<<dim3((T_TOK * 64) / 256), 256, 0, stream>>>(x, Wr, br, top_idx, topw, counts);
    scan_kernel<<<1, 1, 0, stream>>>(counts, offs, cursors, tiles);
    scatter_kernel<<<dim3(T_TOK / 256), 256, 0, stream>>>(top_idx, cursors, sorted);
    gemm1_f32_kernel<<<dim3(MAX_TILES, DF / BN), 512, 0, stream>>>(x, Wg, Wu, tiles, sorted, hbuf);
    gemm2_f32_kernel<<<dim3(MAX_TILES, DM / BN), 512, 0, stream>>>(hbuf, Wd, tiles, sorted, topw, out);
  }
}